// Round 1
// baseline (2429.933 us; speedup 1.0000x reference)
//
#include <hip/hip_runtime.h>

typedef _Float16 half_t;
typedef half_t half8 __attribute__((ext_vector_type(8)));
typedef half_t half4 __attribute__((ext_vector_type(4)));
typedef float  floatx4 __attribute__((ext_vector_type(4)));

#define NB 2048
#define NT 20
#define CD 512
#define HD 1024
#define VD 2048
#define QD 1024

__device__ __forceinline__ float sigmoidf_(float x) {
    return 1.0f / (1.0f + __expf(-x));
}
__device__ __forceinline__ float lrelu_(float x) {
    return x > 0.0f ? x : 0.01f * x;
}

template <int N>
__device__ __forceinline__ void zero_acc(floatx4 (*acc)[2][2]) {
#pragma unroll
    for (int g = 0; g < N; ++g)
#pragma unroll
        for (int a = 0; a < 2; ++a)
#pragma unroll
            for (int b = 0; b < 2; ++b)
                acc[g][a][b] = (floatx4){0.f, 0.f, 0.f, 0.f};
}

// ---- generic staged MFMA GEMM phase ----
// Block: 256 threads = 4 waves in 2x2. Output: rows [m0,m0+64), per-gate cols
// [c0,c0+64). Computes acc[g] += A[64xK] * W_g[64xK]^T for g in [0,NG).
// A row stride = lda, W row stride = K, W gate-g base = W + g*gate_stride.
// lds must hold (1+NG)*4096 half_t.
template <int NG>
__device__ __forceinline__ void gemm_phase(
    const half_t* __restrict__ A, int lda,
    const half_t* __restrict__ W, int gate_stride, int K,
    int m0, int c0, half_t* lds, floatx4 (*acc)[2][2])
{
    const int tid  = threadIdx.x;
    const int lane = tid & 63;
    const int wid  = tid >> 6;
    const int wr   = (wid >> 1) * 32;
    const int wc   = (wid & 1) * 32;
    const int srow = tid >> 3;          // 0..31
    const int scol = (tid & 7) * 8;     // 0..56
    const int frow = lane & 15;
    const int fk   = (lane >> 4) * 8;

    for (int k0 = 0; k0 < K; k0 += 64) {
        __syncthreads();
        {
            const half_t* s = A + (m0 + srow) * lda + k0 + scol;
            *(uint4*)(lds + srow * 64 + scol)        = *(const uint4*)s;
            *(uint4*)(lds + (srow + 32) * 64 + scol) = *(const uint4*)(s + 32 * lda);
        }
#pragma unroll
        for (int g = 0; g < NG; ++g) {
            const half_t* s = W + g * gate_stride + (c0 + srow) * K + k0 + scol;
            half_t* d = lds + (1 + g) * 4096;
            *(uint4*)(d + srow * 64 + scol)        = *(const uint4*)s;
            *(uint4*)(d + (srow + 32) * 64 + scol) = *(const uint4*)(s + 32 * K);
        }
        __syncthreads();
#pragma unroll
        for (int kk = 0; kk < 2; ++kk) {
            half8 af[2];
#pragma unroll
            for (int im = 0; im < 2; ++im)
                af[im] = *(const half8*)(lds + (wr + im * 16 + frow) * 64 + kk * 32 + fk);
#pragma unroll
            for (int g = 0; g < NG; ++g) {
#pragma unroll
                for (int in = 0; in < 2; ++in) {
                    half8 bf = *(const half8*)(lds + (1 + g) * 4096 +
                                               (wc + in * 16 + frow) * 64 + kk * 32 + fk);
#pragma unroll
                    for (int im = 0; im < 2; ++im)
                        acc[g][im][in] = __builtin_amdgcn_mfma_f32_16x16x32_f16(
                            af[im], bf, acc[g][im][in], 0, 0, 0);
                }
            }
        }
    }
}

// fp32 -> fp16 conversion, 4 elems/thread; n must be divisible by 1024
__global__ void cvt_kernel(const float* __restrict__ src, half_t* __restrict__ dst, int n) {
    int i = (blockIdx.x * 256 + threadIdx.x) * 4;
    if (i < n) {
        float4 f = *(const float4*)(src + i);
        half4 h = {(half_t)f.x, (half_t)f.y, (half_t)f.z, (half_t)f.w};
        *(half4*)(dst + i) = h;
    }
}

// fvq = leaky(v@Wv^T) + leaky(q@Wq^T)   [NB, CD] fp32
__global__ __launch_bounds__(256) void fvq_kernel(
    const half_t* __restrict__ v_h, const half_t* __restrict__ wv_w,
    const half_t* __restrict__ q_h, const half_t* __restrict__ wq_w,
    float* __restrict__ fvq)
{
    __shared__ half_t lds[2 * 4096];
    floatx4 acc[2][2][2];
    zero_acc<2>(acc);
    const int m0 = blockIdx.y * 64, c0 = blockIdx.x * 64;
    gemm_phase<1>(v_h, VD, wv_w, 0, VD, m0, c0, lds, acc);
    gemm_phase<1>(q_h, QD, wq_w, 0, QD, m0, c0, lds, acc + 1);

    const int lane = threadIdx.x & 63;
    const int wid = threadIdx.x >> 6;
    const int wr = (wid >> 1) * 32, wc = (wid & 1) * 32;
#pragma unroll
    for (int im = 0; im < 2; ++im)
#pragma unroll
    for (int in = 0; in < 2; ++in) {
        const int mb = m0 + wr + im * 16 + (lane >> 4) * 4;
        const int c  = c0 + wc + in * 16 + (lane & 15);
#pragma unroll
        for (int j = 0; j < 4; ++j) {
            const int m = mb + j;
            fvq[m * CD + c] = lrelu_(acc[0][im][in][j]) + lrelu_(acc[1][im][in][j]);
        }
    }
}

// step 1: h1' = GRUCell(x_t, h1); att = sigmoid(h1'*fvq)*x_t; write alphas
__global__ __launch_bounds__(256) void step1_kernel(
    const half_t* __restrict__ cap_h,
    const half_t* __restrict__ wih1, const half_t* __restrict__ whh1,
    const float* __restrict__ b_ih1, const float* __restrict__ b_hh1,
    const half_t* __restrict__ h1_src, half_t* __restrict__ h1_dst,
    const float* __restrict__ fvq, const float* __restrict__ caption,
    const int* __restrict__ cap_len,
    half_t* __restrict__ att_h, float* __restrict__ alphas, int t)
{
    __shared__ half_t lds[4 * 4096];
    floatx4 acc[6][2][2];
    zero_acc<6>(acc);
    const int m0 = blockIdx.y * 64, c0 = blockIdx.x * 64;
    // gi = x_t @ w_ih1^T : x_t rows live at (m*NT + t)*CD
    gemm_phase<3>(cap_h + t * CD, NT * CD, wih1, CD * CD, CD, m0, c0, lds, acc);
    // gh = h1 @ w_hh1^T
    gemm_phase<3>(h1_src, CD, whh1, CD * CD, CD, m0, c0, lds, acc + 3);

    const int lane = threadIdx.x & 63;
    const int wid = threadIdx.x >> 6;
    const int wr = (wid >> 1) * 32, wc = (wid & 1) * 32;
#pragma unroll
    for (int im = 0; im < 2; ++im)
#pragma unroll
    for (int in = 0; in < 2; ++in) {
        const int mb = m0 + wr + im * 16 + (lane >> 4) * 4;
        const int c  = c0 + wc + in * 16 + (lane & 15);
        const float bir = b_ih1[c], biz = b_ih1[CD + c], bin_ = b_ih1[2 * CD + c];
        const float bhr = b_hh1[c], bhz = b_hh1[CD + c], bhn = b_hh1[2 * CD + c];
#pragma unroll
        for (int j = 0; j < 4; ++j) {
            const int m = mb + j;
            const float r = sigmoidf_(acc[0][im][in][j] + bir + acc[3][im][in][j] + bhr);
            const float z = sigmoidf_(acc[1][im][in][j] + biz + acc[4][im][in][j] + bhz);
            const float n = tanhf(acc[2][im][in][j] + bin_ + r * (acc[5][im][in][j] + bhn));
            const float h_old = (float)h1_src[m * CD + c];
            const bool act = t < cap_len[m];
            const float h_new = act ? ((1.f - z) * n + z * h_old) : h_old;
            const float x = caption[(m * NT + t) * CD + c];
            const float at = sigmoidf_(h_new * fvq[m * CD + c]) * x;
            h1_dst[m * CD + c] = (half_t)h_new;
            att_h[m * CD + c]  = (half_t)at;
            alphas[(m * NT + t) * CD + c] = act ? at : 0.f;
        }
    }
}

// step 2: h2' = GRUCell(att, h2)
__global__ __launch_bounds__(256) void step2_kernel(
    const half_t* __restrict__ att_h,
    const half_t* __restrict__ wih2, const half_t* __restrict__ whh2,
    const float* __restrict__ b_ih2, const float* __restrict__ b_hh2,
    const half_t* __restrict__ h2_src, half_t* __restrict__ h2_dst,
    const int* __restrict__ cap_len, int t)
{
    __shared__ half_t lds[4 * 4096];
    floatx4 acc[6][2][2];
    zero_acc<6>(acc);
    const int m0 = blockIdx.y * 64, c0 = blockIdx.x * 64;
    gemm_phase<3>(att_h, CD, wih2, HD * CD, CD, m0, c0, lds, acc);
    gemm_phase<3>(h2_src, HD, whh2, HD * HD, HD, m0, c0, lds, acc + 3);

    const int lane = threadIdx.x & 63;
    const int wid = threadIdx.x >> 6;
    const int wr = (wid >> 1) * 32, wc = (wid & 1) * 32;
#pragma unroll
    for (int im = 0; im < 2; ++im)
#pragma unroll
    for (int in = 0; in < 2; ++in) {
        const int mb = m0 + wr + im * 16 + (lane >> 4) * 4;
        const int c  = c0 + wc + in * 16 + (lane & 15);
        const float bir = b_ih2[c], biz = b_ih2[HD + c], bin_ = b_ih2[2 * HD + c];
        const float bhr = b_hh2[c], bhz = b_hh2[HD + c], bhn = b_hh2[2 * HD + c];
#pragma unroll
        for (int j = 0; j < 4; ++j) {
            const int m = mb + j;
            const float r = sigmoidf_(acc[0][im][in][j] + bir + acc[3][im][in][j] + bhr);
            const float z = sigmoidf_(acc[1][im][in][j] + biz + acc[4][im][in][j] + bhz);
            const float n = tanhf(acc[2][im][in][j] + bin_ + r * (acc[5][im][in][j] + bhn));
            const float h_old = (float)h2_src[m * HD + c];
            const bool act = t < cap_len[m];
            const float h_new = act ? ((1.f - z) * n + z * h_old) : h_old;
            h2_dst[m * HD + c] = (half_t)h_new;
        }
    }
}

// step 3: out = max(out, active ? leaky(h2 @ Wfc^T) : skip)
__global__ __launch_bounds__(256) void step3_kernel(
    const half_t* __restrict__ h2_cur, const half_t* __restrict__ wfc,
    const int* __restrict__ cap_len, float* __restrict__ outmax, int t)
{
    __shared__ half_t lds[2 * 4096];
    floatx4 acc[1][2][2];
    zero_acc<1>(acc);
    const int m0 = blockIdx.y * 64, c0 = blockIdx.x * 64;
    gemm_phase<1>(h2_cur, HD, wfc, 0, HD, m0, c0, lds, acc);

    const int lane = threadIdx.x & 63;
    const int wid = threadIdx.x >> 6;
    const int wr = (wid >> 1) * 32, wc = (wid & 1) * 32;
#pragma unroll
    for (int im = 0; im < 2; ++im)
#pragma unroll
    for (int in = 0; in < 2; ++in) {
        const int mb = m0 + wr + im * 16 + (lane >> 4) * 4;
        const int c  = c0 + wc + in * 16 + (lane & 15);
#pragma unroll
        for (int j = 0; j < 4; ++j) {
            const int m = mb + j;
            if (t < cap_len[m]) {
                const float v0 = lrelu_(acc[0][im][in][j]);
                float* p = &outmax[m * HD + c];
                *p = fmaxf(*p, v0);
            }
        }
    }
}

extern "C" void kernel_launch(void* const* d_in, const int* in_sizes, int n_in,
                              void* d_out, int out_size, void* d_ws, size_t ws_size,
                              hipStream_t stream)
{
    (void)in_sizes; (void)n_in; (void)out_size; (void)ws_size;
    const float* v     = (const float*)d_in[0];
    const float* q     = (const float*)d_in[1];
    const float* cap   = (const float*)d_in[2];
    const int*   cap_len = (const int*)d_in[3];
    const float* w_ih1 = (const float*)d_in[4];
    const float* w_hh1 = (const float*)d_in[5];
    const float* b_ih1 = (const float*)d_in[6];
    const float* b_hh1 = (const float*)d_in[7];
    const float* w_ih2 = (const float*)d_in[8];
    const float* w_hh2 = (const float*)d_in[9];
    const float* b_ih2 = (const float*)d_in[10];
    const float* b_hh2 = (const float*)d_in[11];
    const float* Wv    = (const float*)d_in[12];
    const float* Wq    = (const float*)d_in[13];
    const float* Wfc   = (const float*)d_in[14];

    float* out_max = (float*)d_out;               // [NB, HD]
    float* alphas  = (float*)d_out + (size_t)NB * HD;  // [NB, NT, CD]

    half_t* p = (half_t*)d_ws;
    half_t* v_h    = p; p += (size_t)NB * VD;
    half_t* q_h    = p; p += (size_t)NB * QD;
    half_t* cap_h  = p; p += (size_t)NB * NT * CD;
    half_t* wih1_h = p; p += 3 * CD * CD;
    half_t* whh1_h = p; p += 3 * CD * CD;
    half_t* wih2_h = p; p += 3 * HD * CD;
    half_t* whh2_h = p; p += 3 * HD * HD;
    half_t* wfc_h  = p; p += HD * HD;
    half_t* wv_h   = p; p += CD * VD;
    half_t* wq_h   = p; p += CD * QD;
    half_t* h1b[2]; h1b[0] = p; p += (size_t)NB * CD; h1b[1] = p; p += (size_t)NB * CD;
    half_t* h2b[2]; h2b[0] = p; p += (size_t)NB * HD; h2b[1] = p; p += (size_t)NB * HD;
    half_t* att_h  = p; p += (size_t)NB * CD;
    float* fvq = (float*)p;

    hipMemsetAsync(d_out, 0, (size_t)NB * HD * sizeof(float), stream);
    hipMemsetAsync(h1b[0], 0, (size_t)NB * CD * sizeof(half_t), stream);
    hipMemsetAsync(h2b[0], 0, (size_t)NB * HD * sizeof(half_t), stream);

    auto cvt = [&](const float* s, half_t* d, int n) {
        cvt_kernel<<<n / 1024, 256, 0, stream>>>(s, d, n);
    };
    cvt(v, v_h, NB * VD);
    cvt(q, q_h, NB * QD);
    cvt(cap, cap_h, NB * NT * CD);
    cvt(w_ih1, wih1_h, 3 * CD * CD);
    cvt(w_hh1, whh1_h, 3 * CD * CD);
    cvt(w_ih2, wih2_h, 3 * HD * CD);
    cvt(w_hh2, whh2_h, 3 * HD * HD);
    cvt(Wfc, wfc_h, HD * HD);
    cvt(Wv, wv_h, CD * VD);
    cvt(Wq, wq_h, CD * QD);

    fvq_kernel<<<dim3(CD / 64, NB / 64), 256, 0, stream>>>(v_h, wv_h, q_h, wq_h, fvq);

    for (int t = 0; t < NT; ++t) {
        const int s = t & 1, d = s ^ 1;
        step1_kernel<<<dim3(CD / 64, NB / 64), 256, 0, stream>>>(
            cap_h, wih1_h, whh1_h, b_ih1, b_hh1, h1b[s], h1b[d],
            fvq, cap, cap_len, att_h, alphas, t);
        step2_kernel<<<dim3(HD / 64, NB / 64), 256, 0, stream>>>(
            att_h, wih2_h, whh2_h, b_ih2, b_hh2, h2b[s], h2b[d], cap_len, t);
        step3_kernel<<<dim3(HD / 64, NB / 64), 256, 0, stream>>>(
            h2b[d], wfc_h, cap_len, out_max, t);
    }
}

// Round 2
// 2069.537 us; speedup vs baseline: 1.1741x; 1.1741x over previous
//
#include <hip/hip_runtime.h>

typedef _Float16 half_t;
typedef half_t half8 __attribute__((ext_vector_type(8)));
typedef half_t half4 __attribute__((ext_vector_type(4)));
typedef float  floatx4 __attribute__((ext_vector_type(4)));

#define NB 2048
#define NT 20
#define CD 512
#define HD 1024
#define VD 2048
#define QD 1024

// LDS tile: 64 rows x 64 cols, padded stride 72 halves (144 B) so fragment
// reads (16 rows, same col offset) hit banks 4r%32 -> only 2-way aliasing
// (r vs r+8), which is free on gfx950 (m136). Stride stays 16B-aligned for
// uint4/half8 access. 64-stride was 128 B = 32 banks -> 16-way conflicts
// (4.7M SQ_LDS_BANK_CONFLICT per fvq dispatch in round 1).
#define LDST 72
#define TSZ  (64 * LDST)

__device__ __forceinline__ float sigmoidf_(float x) {
    return 1.0f / (1.0f + __expf(-x));
}
__device__ __forceinline__ float tanhf_(float x) {
    return 1.0f - 2.0f / (1.0f + __expf(2.0f * x));
}
__device__ __forceinline__ float lrelu_(float x) {
    return x > 0.0f ? x : 0.01f * x;
}

template <int N>
__device__ __forceinline__ void zero_acc(floatx4 (*acc)[2][2]) {
#pragma unroll
    for (int g = 0; g < N; ++g)
#pragma unroll
        for (int a = 0; a < 2; ++a)
#pragma unroll
            for (int b = 0; b < 2; ++b)
                acc[g][a][b] = (floatx4){0.f, 0.f, 0.f, 0.f};
}

// ---- generic staged MFMA GEMM phase ----
// Block: 256 threads = 4 waves in 2x2. Output: rows [m0,m0+64), per-gate cols
// [c0,c0+64). Computes acc[g] += A[64xK] * W_g[64xK]^T for g in [0,NG).
// A row stride = lda, W row stride = K, W gate-g base = W + g*gate_stride.
// lds must hold (1+NG)*TSZ half_t.
template <int NG>
__device__ __forceinline__ void gemm_phase(
    const half_t* __restrict__ A, int lda,
    const half_t* __restrict__ W, int gate_stride, int K,
    int m0, int c0, half_t* lds, floatx4 (*acc)[2][2])
{
    const int tid  = threadIdx.x;
    const int lane = tid & 63;
    const int wid  = tid >> 6;
    const int wr   = (wid >> 1) * 32;
    const int wc   = (wid & 1) * 32;
    const int srow = tid >> 3;          // 0..31
    const int scol = (tid & 7) * 8;     // 0..56
    const int frow = lane & 15;
    const int fk   = (lane >> 4) * 8;

    for (int k0 = 0; k0 < K; k0 += 64) {
        __syncthreads();
        {
            const half_t* s = A + (m0 + srow) * lda + k0 + scol;
            *(uint4*)(lds + srow * LDST + scol)        = *(const uint4*)s;
            *(uint4*)(lds + (srow + 32) * LDST + scol) = *(const uint4*)(s + 32 * lda);
        }
#pragma unroll
        for (int g = 0; g < NG; ++g) {
            const half_t* s = W + g * gate_stride + (c0 + srow) * K + k0 + scol;
            half_t* d = lds + (1 + g) * TSZ;
            *(uint4*)(d + srow * LDST + scol)        = *(const uint4*)s;
            *(uint4*)(d + (srow + 32) * LDST + scol) = *(const uint4*)(s + 32 * K);
        }
        __syncthreads();
#pragma unroll
        for (int kk = 0; kk < 2; ++kk) {
            half8 af[2];
#pragma unroll
            for (int im = 0; im < 2; ++im)
                af[im] = *(const half8*)(lds + (wr + im * 16 + frow) * LDST + kk * 32 + fk);
#pragma unroll
            for (int g = 0; g < NG; ++g) {
#pragma unroll
                for (int in = 0; in < 2; ++in) {
                    half8 bf = *(const half8*)(lds + (1 + g) * TSZ +
                                               (wc + in * 16 + frow) * LDST + kk * 32 + fk);
#pragma unroll
                    for (int im = 0; im < 2; ++im)
                        acc[g][im][in] = __builtin_amdgcn_mfma_f32_16x16x32_f16(
                            af[im], bf, acc[g][im][in], 0, 0, 0);
                }
            }
        }
    }
}

// fp32 -> fp16 conversion, 4 elems/thread; n must be divisible by 1024
__global__ void cvt_kernel(const float* __restrict__ src, half_t* __restrict__ dst, int n) {
    int i = (blockIdx.x * 256 + threadIdx.x) * 4;
    if (i < n) {
        float4 f = *(const float4*)(src + i);
        half4 h = {(half_t)f.x, (half_t)f.y, (half_t)f.z, (half_t)f.w};
        *(half4*)(dst + i) = h;
    }
}

// fvq = leaky(v@Wv^T) + leaky(q@Wq^T)   [NB, CD] fp32
__global__ __launch_bounds__(256) void fvq_kernel(
    const half_t* __restrict__ v_h, const half_t* __restrict__ wv_w,
    const half_t* __restrict__ q_h, const half_t* __restrict__ wq_w,
    float* __restrict__ fvq)
{
    __shared__ half_t lds[2 * TSZ];
    floatx4 acc[2][2][2];
    zero_acc<2>(acc);
    const int m0 = blockIdx.y * 64, c0 = blockIdx.x * 64;
    gemm_phase<1>(v_h, VD, wv_w, 0, VD, m0, c0, lds, acc);
    gemm_phase<1>(q_h, QD, wq_w, 0, QD, m0, c0, lds, acc + 1);

    const int lane = threadIdx.x & 63;
    const int wid = threadIdx.x >> 6;
    const int wr = (wid >> 1) * 32, wc = (wid & 1) * 32;
#pragma unroll
    for (int im = 0; im < 2; ++im)
#pragma unroll
    for (int in = 0; in < 2; ++in) {
        const int mb = m0 + wr + im * 16 + (lane >> 4) * 4;
        const int c  = c0 + wc + in * 16 + (lane & 15);
#pragma unroll
        for (int j = 0; j < 4; ++j) {
            const int m = mb + j;
            fvq[m * CD + c] = lrelu_(acc[0][im][in][j]) + lrelu_(acc[1][im][in][j]);
        }
    }
}

// step 1: h1' = GRUCell(x_t, h1); att = sigmoid(h1'*fvq)*x_t; write alphas
__global__ __launch_bounds__(256) void step1_kernel(
    const half_t* __restrict__ cap_h,
    const half_t* __restrict__ wih1, const half_t* __restrict__ whh1,
    const float* __restrict__ b_ih1, const float* __restrict__ b_hh1,
    const half_t* __restrict__ h1_src, half_t* __restrict__ h1_dst,
    const float* __restrict__ fvq, const float* __restrict__ caption,
    const int* __restrict__ cap_len,
    half_t* __restrict__ att_h, float* __restrict__ alphas, int t)
{
    __shared__ half_t lds[4 * TSZ];
    floatx4 acc[6][2][2];
    zero_acc<6>(acc);
    const int m0 = blockIdx.y * 64, c0 = blockIdx.x * 64;
    // gi = x_t @ w_ih1^T : x_t rows live at (m*NT + t)*CD
    gemm_phase<3>(cap_h + t * CD, NT * CD, wih1, CD * CD, CD, m0, c0, lds, acc);
    // gh = h1 @ w_hh1^T
    gemm_phase<3>(h1_src, CD, whh1, CD * CD, CD, m0, c0, lds, acc + 3);

    const int lane = threadIdx.x & 63;
    const int wid = threadIdx.x >> 6;
    const int wr = (wid >> 1) * 32, wc = (wid & 1) * 32;
#pragma unroll
    for (int im = 0; im < 2; ++im)
#pragma unroll
    for (int in = 0; in < 2; ++in) {
        const int mb = m0 + wr + im * 16 + (lane >> 4) * 4;
        const int c  = c0 + wc + in * 16 + (lane & 15);
        const float bir = b_ih1[c], biz = b_ih1[CD + c], bin_ = b_ih1[2 * CD + c];
        const float bhr = b_hh1[c], bhz = b_hh1[CD + c], bhn = b_hh1[2 * CD + c];
#pragma unroll
        for (int j = 0; j < 4; ++j) {
            const int m = mb + j;
            const float r = sigmoidf_(acc[0][im][in][j] + bir + acc[3][im][in][j] + bhr);
            const float z = sigmoidf_(acc[1][im][in][j] + biz + acc[4][im][in][j] + bhz);
            const float n = tanhf_(acc[2][im][in][j] + bin_ + r * (acc[5][im][in][j] + bhn));
            const float h_old = (float)h1_src[m * CD + c];
            const bool act = t < cap_len[m];
            const float h_new = act ? ((1.f - z) * n + z * h_old) : h_old;
            const float x = caption[(m * NT + t) * CD + c];
            const float at = sigmoidf_(h_new * fvq[m * CD + c]) * x;
            h1_dst[m * CD + c] = (half_t)h_new;
            att_h[m * CD + c]  = (half_t)at;
            alphas[(m * NT + t) * CD + c] = act ? at : 0.f;
        }
    }
}

// step 2: h2' = GRUCell(att, h2)
__global__ __launch_bounds__(256) void step2_kernel(
    const half_t* __restrict__ att_h,
    const half_t* __restrict__ wih2, const half_t* __restrict__ whh2,
    const float* __restrict__ b_ih2, const float* __restrict__ b_hh2,
    const half_t* __restrict__ h2_src, half_t* __restrict__ h2_dst,
    const int* __restrict__ cap_len, int t)
{
    __shared__ half_t lds[4 * TSZ];
    floatx4 acc[6][2][2];
    zero_acc<6>(acc);
    const int m0 = blockIdx.y * 64, c0 = blockIdx.x * 64;
    gemm_phase<3>(att_h, CD, wih2, HD * CD, CD, m0, c0, lds, acc);
    gemm_phase<3>(h2_src, HD, whh2, HD * HD, HD, m0, c0, lds, acc + 3);

    const int lane = threadIdx.x & 63;
    const int wid = threadIdx.x >> 6;
    const int wr = (wid >> 1) * 32, wc = (wid & 1) * 32;
#pragma unroll
    for (int im = 0; im < 2; ++im)
#pragma unroll
    for (int in = 0; in < 2; ++in) {
        const int mb = m0 + wr + im * 16 + (lane >> 4) * 4;
        const int c  = c0 + wc + in * 16 + (lane & 15);
        const float bir = b_ih2[c], biz = b_ih2[HD + c], bin_ = b_ih2[2 * HD + c];
        const float bhr = b_hh2[c], bhz = b_hh2[HD + c], bhn = b_hh2[2 * HD + c];
#pragma unroll
        for (int j = 0; j < 4; ++j) {
            const int m = mb + j;
            const float r = sigmoidf_(acc[0][im][in][j] + bir + acc[3][im][in][j] + bhr);
            const float z = sigmoidf_(acc[1][im][in][j] + biz + acc[4][im][in][j] + bhz);
            const float n = tanhf_(acc[2][im][in][j] + bin_ + r * (acc[5][im][in][j] + bhn));
            const float h_old = (float)h2_src[m * HD + c];
            const bool act = t < cap_len[m];
            const float h_new = act ? ((1.f - z) * n + z * h_old) : h_old;
            h2_dst[m * HD + c] = (half_t)h_new;
        }
    }
}

// step 3: out = max(out, active ? leaky(h2 @ Wfc^T) : skip)
__global__ __launch_bounds__(256) void step3_kernel(
    const half_t* __restrict__ h2_cur, const half_t* __restrict__ wfc,
    const int* __restrict__ cap_len, float* __restrict__ outmax, int t)
{
    __shared__ half_t lds[2 * TSZ];
    floatx4 acc[1][2][2];
    zero_acc<1>(acc);
    const int m0 = blockIdx.y * 64, c0 = blockIdx.x * 64;
    gemm_phase<1>(h2_cur, HD, wfc, 0, HD, m0, c0, lds, acc);

    const int lane = threadIdx.x & 63;
    const int wid = threadIdx.x >> 6;
    const int wr = (wid >> 1) * 32, wc = (wid & 1) * 32;
#pragma unroll
    for (int im = 0; im < 2; ++im)
#pragma unroll
    for (int in = 0; in < 2; ++in) {
        const int mb = m0 + wr + im * 16 + (lane >> 4) * 4;
        const int c  = c0 + wc + in * 16 + (lane & 15);
#pragma unroll
        for (int j = 0; j < 4; ++j) {
            const int m = mb + j;
            if (t < cap_len[m]) {
                const float v0 = lrelu_(acc[0][im][in][j]);
                float* p = &outmax[m * HD + c];
                *p = fmaxf(*p, v0);
            }
        }
    }
}

extern "C" void kernel_launch(void* const* d_in, const int* in_sizes, int n_in,
                              void* d_out, int out_size, void* d_ws, size_t ws_size,
                              hipStream_t stream)
{
    (void)in_sizes; (void)n_in; (void)out_size; (void)ws_size;
    const float* v     = (const float*)d_in[0];
    const float* q     = (const float*)d_in[1];
    const float* cap   = (const float*)d_in[2];
    const int*   cap_len = (const int*)d_in[3];
    const float* w_ih1 = (const float*)d_in[4];
    const float* w_hh1 = (const float*)d_in[5];
    const float* b_ih1 = (const float*)d_in[6];
    const float* b_hh1 = (const float*)d_in[7];
    const float* w_ih2 = (const float*)d_in[8];
    const float* w_hh2 = (const float*)d_in[9];
    const float* b_ih2 = (const float*)d_in[10];
    const float* b_hh2 = (const float*)d_in[11];
    const float* Wv    = (const float*)d_in[12];
    const float* Wq    = (const float*)d_in[13];
    const float* Wfc   = (const float*)d_in[14];

    float* out_max = (float*)d_out;               // [NB, HD]
    float* alphas  = (float*)d_out + (size_t)NB * HD;  // [NB, NT, CD]

    half_t* p = (half_t*)d_ws;
    half_t* v_h    = p; p += (size_t)NB * VD;
    half_t* q_h    = p; p += (size_t)NB * QD;
    half_t* cap_h  = p; p += (size_t)NB * NT * CD;
    half_t* wih1_h = p; p += 3 * CD * CD;
    half_t* whh1_h = p; p += 3 * CD * CD;
    half_t* wih2_h = p; p += 3 * HD * CD;
    half_t* whh2_h = p; p += 3 * HD * HD;
    half_t* wfc_h  = p; p += HD * HD;
    half_t* wv_h   = p; p += CD * VD;
    half_t* wq_h   = p; p += CD * QD;
    half_t* h1b[2]; h1b[0] = p; p += (size_t)NB * CD; h1b[1] = p; p += (size_t)NB * CD;
    half_t* h2b[2]; h2b[0] = p; p += (size_t)NB * HD; h2b[1] = p; p += (size_t)NB * HD;
    half_t* att_h  = p; p += (size_t)NB * CD;
    float* fvq = (float*)p;

    hipMemsetAsync(d_out, 0, (size_t)NB * HD * sizeof(float), stream);
    hipMemsetAsync(h1b[0], 0, (size_t)NB * CD * sizeof(half_t), stream);
    hipMemsetAsync(h2b[0], 0, (size_t)NB * HD * sizeof(half_t), stream);

    auto cvt = [&](const float* s, half_t* d, int n) {
        cvt_kernel<<<n / 1024, 256, 0, stream>>>(s, d, n);
    };
    cvt(v, v_h, NB * VD);
    cvt(q, q_h, NB * QD);
    cvt(cap, cap_h, NB * NT * CD);
    cvt(w_ih1, wih1_h, 3 * CD * CD);
    cvt(w_hh1, whh1_h, 3 * CD * CD);
    cvt(w_ih2, wih2_h, 3 * HD * CD);
    cvt(w_hh2, whh2_h, 3 * HD * HD);
    cvt(Wfc, wfc_h, HD * HD);
    cvt(Wv, wv_h, CD * VD);
    cvt(Wq, wq_h, CD * QD);

    fvq_kernel<<<dim3(CD / 64, NB / 64), 256, 0, stream>>>(v_h, wv_h, q_h, wq_h, fvq);

    for (int t = 0; t < NT; ++t) {
        const int s = t & 1, d = s ^ 1;
        step1_kernel<<<dim3(CD / 64, NB / 64), 256, 0, stream>>>(
            cap_h, wih1_h, whh1_h, b_ih1, b_hh1, h1b[s], h1b[d],
            fvq, cap, cap_len, att_h, alphas, t);
        step2_kernel<<<dim3(HD / 64, NB / 64), 256, 0, stream>>>(
            att_h, wih2_h, whh2_h, b_ih2, b_hh2, h2b[s], h2b[d], cap_len, t);
        step3_kernel<<<dim3(HD / 64, NB / 64), 256, 0, stream>>>(
            h2b[d], wfc_h, cap_len, out_max, t);
    }
}